// Round 1
// baseline (194.752 us; speedup 1.0000x reference)
//
#include <hip/hip_runtime.h>
#include <hip/hip_bf16.h>

typedef __attribute__((ext_vector_type(4))) float f32x4;
typedef __attribute__((ext_vector_type(8))) short bf16x8;
typedef __attribute__((ext_vector_type(4))) short short4v;

// fp32 -> bf16 bits, round-to-nearest-even
__device__ __forceinline__ unsigned short f2bf(float f) {
  unsigned int u = __builtin_bit_cast(unsigned int, f);
  u += 0x7FFFu + ((u >> 16) & 1u);
  return (unsigned short)(u >> 16);
}

// ---------------------------------------------------------------------------
// Weight packing: fragment-order bf16 so main kernels load 16B/lane coalesced.
// Apack[chunk][t][lane][j] = Acat[chunk*32 + (lane>>4)*8 + j][t*16 + (lane&15)]
//   chunk 0..127 (K=4096/32), t 0..5 (N=96/16)   -> 393216 bf16 = 768 KiB
// ---------------------------------------------------------------------------
__global__ __launch_bounds__(256) void pack_A(
    const float* __restrict__ Af, const float* __restrict__ Am,
    const float* __restrict__ As, short* __restrict__ Apack)
{
  unsigned idx = blockIdx.x * 256u + threadIdx.x;   // < 393216
  unsigned j = idx & 7u, lane = (idx >> 3) & 63u, rest = idx >> 9;
  unsigned t = rest % 6u, chunk = rest / 6u;
  unsigned k = chunk * 32u + ((lane >> 4) << 3) + j;
  unsigned c = t * 16u + (lane & 15u);
  float v;
  if (c < 32u)      v = Af[k * 32u + c];
  else if (c < 64u) v = Am[k * 32u + (c - 32u)];
  else              v = As[k * 32u + (c - 64u)];
  Apack[idx] = (short)f2bf(v);
}

// Bpack[kc][nt][lane][j] = SCALE * Bcat[kc*32 + (lane>>4)*8 + j][nt*16 + (lane&15)]
//   kc 0..2 (K=96/32), nt 0..255 (N=4096/16)     -> 393216 bf16 = 768 KiB
__global__ __launch_bounds__(256) void pack_B(
    const float* __restrict__ Bf, const float* __restrict__ Bm,
    const float* __restrict__ Bs, short* __restrict__ Bpack)
{
  unsigned idx = blockIdx.x * 256u + threadIdx.x;   // < 393216
  unsigned j = idx & 7u, lane = (idx >> 3) & 63u, rest = idx >> 9;
  unsigned nt = rest & 255u, kc = rest >> 8;
  unsigned k = kc * 32u + ((lane >> 4) << 3) + j;
  unsigned n = nt * 16u + (lane & 15u);
  float v;
  if (k < 32u)      v = Bf[k * 4096u + n];
  else if (k < 64u) v = Bm[(k - 32u) * 4096u + n];
  else              v = Bs[(k - 64u) * 4096u + n];
  Bpack[idx] = (short)f2bf(v * 0.03125f);           // fold SCALE = 1/32
}

// ---------------------------------------------------------------------------
// Stage 1: hpart[ks][16384][96] (fp32) = x[:, ks*1024:(ks+1)*1024] @ Acat-slice
// grid 1024 = 256 row-blocks (64 rows) x KS=4 k-slices; 4 waves/block,
// each wave one 16-row M-tile x 96 cols. 16 waves/CU hides HBM latency.
// ---------------------------------------------------------------------------
__global__ __launch_bounds__(256, 4) void lora_stage1(
    const float* __restrict__ x, const short* __restrict__ Apack,
    float* __restrict__ hpart)
{
  const int rowblk = blockIdx.x & 255;
  const int ks     = blockIdx.x >> 8;
  const int tid = threadIdx.x;
  const int w = tid >> 6, l = tid & 63;
  const int lm = l & 15, lk = l >> 4;
  const int row = rowblk * 64 + w * 16 + lm;

  const float* xp = x + (size_t)row * 4096 + ks * 1024 + lk * 8;
  const short* ap = Apack + (size_t)(ks * 32) * 3072 + (size_t)l * 8; // chunk stride 3072 shorts

  f32x4 acc[6];
#pragma unroll
  for (int t = 0; t < 6; ++t) acc[t] = (f32x4){0.f, 0.f, 0.f, 0.f};

  // depth-2 register pipeline
  f32x4 nx0 = *(const f32x4*)(xp);
  f32x4 nx1 = *(const f32x4*)(xp + 4);
  bf16x8 naf[6];
#pragma unroll
  for (int t = 0; t < 6; ++t) naf[t] = *(const bf16x8*)(ap + t * 512);

  for (int c = 0; c < 32; ++c) {
    f32x4 x0 = nx0, x1 = nx1;
    bf16x8 af[6];
#pragma unroll
    for (int t = 0; t < 6; ++t) af[t] = naf[t];
    if (c < 31) {
      const float* xq = xp + (size_t)(c + 1) * 32;
      nx0 = *(const f32x4*)(xq);
      nx1 = *(const f32x4*)(xq + 4);
      const short* aq = ap + (size_t)(c + 1) * 3072;
#pragma unroll
      for (int t = 0; t < 6; ++t) naf[t] = *(const bf16x8*)(aq + t * 512);
    }
    bf16x8 xf;
    xf[0] = (short)f2bf(x0[0]); xf[1] = (short)f2bf(x0[1]);
    xf[2] = (short)f2bf(x0[2]); xf[3] = (short)f2bf(x0[3]);
    xf[4] = (short)f2bf(x1[0]); xf[5] = (short)f2bf(x1[1]);
    xf[6] = (short)f2bf(x1[2]); xf[7] = (short)f2bf(x1[3]);
#pragma unroll
    for (int t = 0; t < 6; ++t)
      acc[t] = __builtin_amdgcn_mfma_f32_16x16x32_bf16(xf, af[t], acc[t], 0, 0, 0);
  }

  // D layout: col = lane&15, row = (lane>>4)*4 + reg (m89-verified)
  float* hp = hpart + ((size_t)ks * 16384 + (size_t)rowblk * 64 + w * 16 + lk * 4) * 96 + lm;
#pragma unroll
  for (int t = 0; t < 6; ++t)
#pragma unroll
    for (int q = 0; q < 4; ++q)
      hp[(size_t)q * 96 + t * 16] = acc[t][q];
}

// ---------------------------------------------------------------------------
// Stage 2: out[16384][4096] = (sum_ks hpart) @ Bcat * SCALE (SCALE in Bpack)
// grid 4096 = 256 row-blocks (64 rows) x 16 col-blocks (256 cols);
// prologue sums 4 partials -> bf16 LDS [64][104] (padded vs bank conflicts).
// ---------------------------------------------------------------------------
__global__ __launch_bounds__(256, 3) void lora_stage2(
    const float* __restrict__ hpart, const short* __restrict__ Bpack,
    float* __restrict__ out)
{
  const int rb = blockIdx.x >> 4;
  const int cb = blockIdx.x & 15;
  const int tid = threadIdx.x;
  __shared__ short hlds[64][104];

  {
    const f32x4* hv = (const f32x4*)hpart + (size_t)rb * 1536; // 64 rows * 24 f32x4
#pragma unroll
    for (int i = 0; i < 6; ++i) {
      int f = i * 256 + tid;                 // 0..1535, coalesced
      f32x4 s = hv[f];
      s += hv[(size_t)f + 393216];           // + ks slice (16384*96/4)
      s += hv[(size_t)f + 2 * 393216];
      s += hv[(size_t)f + 3 * 393216];
      int r = f / 24, cq = f % 24;
      short4v o;
      o[0] = (short)f2bf(s[0]); o[1] = (short)f2bf(s[1]);
      o[2] = (short)f2bf(s[2]); o[3] = (short)f2bf(s[3]);
      *(short4v*)&hlds[r][cq * 4] = o;
    }
  }
  __syncthreads();

  const int w = tid >> 6, l = tid & 63;
  const int lm = l & 15, lk = l >> 4;

  bf16x8 hf[3];
#pragma unroll
  for (int kc = 0; kc < 3; ++kc)
    hf[kc] = *(const bf16x8*)&hlds[w * 16 + lm][kc * 32 + lk * 8];

  const short* bp = Bpack + (size_t)l * 8;
  f32x4 acc[16];
#pragma unroll
  for (int t = 0; t < 16; ++t) acc[t] = (f32x4){0.f, 0.f, 0.f, 0.f};

#pragma unroll
  for (int kc = 0; kc < 3; ++kc) {
#pragma unroll
    for (int t = 0; t < 16; ++t) {
      bf16x8 bfv = *(const bf16x8*)(bp + (size_t)(kc * 256 + cb * 16 + t) * 512);
      acc[t] = __builtin_amdgcn_mfma_f32_16x16x32_bf16(hf[kc], bfv, acc[t], 0, 0, 0);
    }
  }

  float* op = out + ((size_t)rb * 64 + w * 16 + lk * 4) * 4096 + cb * 256 + lm;
#pragma unroll
  for (int t = 0; t < 16; ++t)
#pragma unroll
    for (int q = 0; q < 4; ++q)
      op[(size_t)q * 4096 + t * 16] = acc[t][q];
}

extern "C" void kernel_launch(void* const* d_in, const int* in_sizes, int n_in,
                              void* d_out, int out_size, void* d_ws, size_t ws_size,
                              hipStream_t stream) {
  const float* x  = (const float*)d_in[0];
  const float* Af = (const float*)d_in[1];
  const float* Bf = (const float*)d_in[2];
  const float* Am = (const float*)d_in[3];
  const float* Bm = (const float*)d_in[4];
  const float* As = (const float*)d_in[5];
  const float* Bs = (const float*)d_in[6];
  float* out = (float*)d_out;

  char* ws = (char*)d_ws;
  short* Apack = (short*)ws;                  // 786432 B
  short* Bpack = (short*)(ws + 786432);       // 786432 B
  float* hpart = (float*)(ws + 2 * 786432);   // 4*16384*96*4 = 25165824 B

  hipLaunchKernelGGL(pack_A, dim3(1536), dim3(256), 0, stream, Af, Am, As, Apack);
  hipLaunchKernelGGL(pack_B, dim3(1536), dim3(256), 0, stream, Bf, Bm, Bs, Bpack);
  hipLaunchKernelGGL(lora_stage1, dim3(1024), dim3(256), 0, stream, x, Apack, hpart);
  hipLaunchKernelGGL(lora_stage2, dim3(4096), dim3(256), 0, stream, hpart, Bpack, out);
}

// Round 2
// 178.457 us; speedup vs baseline: 1.0913x; 1.0913x over previous
//
#include <hip/hip_runtime.h>
#include <hip/hip_bf16.h>

typedef __attribute__((ext_vector_type(4))) float f32x4;
typedef __attribute__((ext_vector_type(8))) short bf16x8;

// fp32 -> bf16 bits, round-to-nearest-even
__device__ __forceinline__ unsigned short f2bf(float f) {
  unsigned int u = __builtin_bit_cast(unsigned int, f);
  u += 0x7FFFu + ((u >> 16) & 1u);
  return (unsigned short)(u >> 16);
}

// ---------------------------------------------------------------------------
// Weight packing (one launch): fragment-order bf16, 16B/lane coalesced loads.
// Apack[chunk][t][lane][j] = Acat[chunk*32 + (lane>>4)*8 + j][t*16 + (lane&15)]
// Bpack[kc][nt][lane][j]   = SCALE * Bcat[kc*32 + (lane>>4)*8 + j][nt*16 + (lane&15)]
// ---------------------------------------------------------------------------
__global__ __launch_bounds__(256) void pack_AB(
    const float* __restrict__ Af, const float* __restrict__ Am,
    const float* __restrict__ As, const float* __restrict__ Bf,
    const float* __restrict__ Bm, const float* __restrict__ Bs,
    short* __restrict__ Apack, short* __restrict__ Bpack)
{
  unsigned idx = blockIdx.x * 256u + threadIdx.x;     // < 786432
  if (idx < 393216u) {
    unsigned j = idx & 7u, lane = (idx >> 3) & 63u, rest = idx >> 9;
    unsigned t = rest % 6u, chunk = rest / 6u;
    unsigned k = chunk * 32u + ((lane >> 4) << 3) + j;
    unsigned c = t * 16u + (lane & 15u);
    float v;
    if (c < 32u)      v = Af[k * 32u + c];
    else if (c < 64u) v = Am[k * 32u + (c - 32u)];
    else              v = As[k * 32u + (c - 64u)];
    Apack[idx] = (short)f2bf(v);
  } else {
    unsigned i2 = idx - 393216u;
    unsigned j = i2 & 7u, lane = (i2 >> 3) & 63u, rest = i2 >> 9;
    unsigned nt = rest & 255u, kc = rest >> 8;
    unsigned k = kc * 32u + ((lane >> 4) << 3) + j;
    unsigned n = nt * 16u + (lane & 15u);
    float v;
    if (k < 32u)      v = Bf[k * 4096u + n];
    else if (k < 64u) v = Bm[(k - 32u) * 4096u + n];
    else              v = Bs[(k - 64u) * 4096u + n];
    Bpack[i2] = (short)f2bf(v * 0.03125f);            // fold SCALE = 1/32
  }
}

// ---------------------------------------------------------------------------
// Fused LoRA: per block, 32 rows -> h[32][96] in LDS -> out tile 32x4096.
// 512 blocks x 512 threads (8 waves). Phase 1: wave (rg,kq) = 16 rows x 1024-K
// quarter, fp32 partials to LDS. Reduce across kq, pack bf16 fragments.
// Phase 2: wave (rg,cg) = 16 rows x 1024 cols in four 256-col chunks.
// Weights (1.5 MiB packed) stay L2-resident; no hpart round-trip.
// ---------------------------------------------------------------------------
__global__ __launch_bounds__(512, 4) void lora_fused(
    const float* __restrict__ x, const short* __restrict__ Apack,
    const short* __restrict__ Bpack, float* __restrict__ out)
{
  const int rb  = blockIdx.x;                 // rows rb*32 .. +32
  const int tid = threadIdx.x;
  const int w = tid >> 6, l = tid & 63;
  const int lm = l & 15, lk = l >> 4;
  const int rg = w >> 2;                      // row-group 0..1 (16 rows)
  const int kq = w & 3;                       // K-quarter (phase 1) / col-quarter (phase 2)

  __shared__ float hp_lds[2][4][16][100];     // fp32 partials, padded (51200 B)
  __shared__ short hfrag[2][3][64][8];        // bf16 MFMA A-fragments (6144 B)

  // ---------------- phase 1: h partials = x-slice @ Apack-slice -------------
  {
    const int row = rb * 32 + rg * 16 + lm;
    const float* xp = x + (size_t)row * 4096 + kq * 1024 + lk * 8;
    const short* ap = Apack + (size_t)(kq * 32) * 3072 + (size_t)l * 8;

    f32x4 acc[6];
#pragma unroll
    for (int t = 0; t < 6; ++t) acc[t] = (f32x4){0.f, 0.f, 0.f, 0.f};

    // depth-2 register pipeline over 32 K-chunks
    f32x4 nx0 = *(const f32x4*)(xp);
    f32x4 nx1 = *(const f32x4*)(xp + 4);
    bf16x8 naf[6];
#pragma unroll
    for (int t = 0; t < 6; ++t) naf[t] = *(const bf16x8*)(ap + t * 512);

    for (int c = 0; c < 32; ++c) {
      f32x4 x0 = nx0, x1 = nx1;
      bf16x8 af[6];
#pragma unroll
      for (int t = 0; t < 6; ++t) af[t] = naf[t];
      if (c < 31) {
        const float* xq = xp + (size_t)(c + 1) * 32;
        nx0 = *(const f32x4*)(xq);
        nx1 = *(const f32x4*)(xq + 4);
        const short* aq = ap + (size_t)(c + 1) * 3072;
#pragma unroll
        for (int t = 0; t < 6; ++t) naf[t] = *(const bf16x8*)(aq + t * 512);
      }
      bf16x8 xf;
      xf[0] = (short)f2bf(x0[0]); xf[1] = (short)f2bf(x0[1]);
      xf[2] = (short)f2bf(x0[2]); xf[3] = (short)f2bf(x0[3]);
      xf[4] = (short)f2bf(x1[0]); xf[5] = (short)f2bf(x1[1]);
      xf[6] = (short)f2bf(x1[2]); xf[7] = (short)f2bf(x1[3]);
#pragma unroll
      for (int t = 0; t < 6; ++t)
        acc[t] = __builtin_amdgcn_mfma_f32_16x16x32_bf16(xf, af[t], acc[t], 0, 0, 0);
    }

    // D layout: M-index = lk*4+q, N-index = lm (m89-verified)
#pragma unroll
    for (int t = 0; t < 6; ++t)
#pragma unroll
      for (int q = 0; q < 4; ++q)
        hp_lds[rg][kq][lk * 4 + q][t * 16 + lm] = acc[t][q];
  }
  __syncthreads();

  // -------- reduce over kq, pack bf16 fragments for phase-2 A-operand -------
  if (tid < 384) {
    const int r = tid / 12, cg = tid % 12;   // row 0..31, col-group of 8
    const int g = r >> 4, ri = r & 15;
    f32x4 s0 = *(const f32x4*)&hp_lds[g][0][ri][cg * 8];
    f32x4 s1 = *(const f32x4*)&hp_lds[g][0][ri][cg * 8 + 4];
#pragma unroll
    for (int q = 1; q < 4; ++q) {
      s0 += *(const f32x4*)&hp_lds[g][q][ri][cg * 8];
      s1 += *(const f32x4*)&hp_lds[g][q][ri][cg * 8 + 4];
    }
    // element (r, cg*8+j) -> fragment lane = (cg&3)*16 + ri, kc = cg>>2
    bf16x8 o;
    o[0] = (short)f2bf(s0[0]); o[1] = (short)f2bf(s0[1]);
    o[2] = (short)f2bf(s0[2]); o[3] = (short)f2bf(s0[3]);
    o[4] = (short)f2bf(s1[0]); o[5] = (short)f2bf(s1[1]);
    o[6] = (short)f2bf(s1[2]); o[7] = (short)f2bf(s1[3]);
    *(bf16x8*)&hfrag[g][cg >> 2][(cg & 3) * 16 + ri][0] = o;
  }
  __syncthreads();

  // ---------------- phase 2: out tile = h @ Bpack ---------------------------
  {
    const int cg = kq;                        // col-quarter 0..3 (1024 cols)
    bf16x8 hf[3];
#pragma unroll
    for (int kc = 0; kc < 3; ++kc)
      hf[kc] = *(const bf16x8*)&hfrag[rg][kc][l][0];  // conflict-free: lane-linear

    const short* bp = Bpack + (size_t)l * 8;

    for (int cc = 0; cc < 4; ++cc) {
      f32x4 acc2[16];
#pragma unroll
      for (int t = 0; t < 16; ++t) acc2[t] = (f32x4){0.f, 0.f, 0.f, 0.f};
      const int ntbase = cg * 64 + cc * 16;
#pragma unroll
      for (int kc = 0; kc < 3; ++kc) {
#pragma unroll
        for (int t = 0; t < 16; ++t) {
          bf16x8 bfv = *(const bf16x8*)(bp + (size_t)(kc * 256 + ntbase + t) * 512);
          acc2[t] = __builtin_amdgcn_mfma_f32_16x16x32_bf16(hf[kc], bfv, acc2[t], 0, 0, 0);
        }
      }
      float* op = out + ((size_t)rb * 32 + rg * 16 + lk * 4) * 4096
                      + cg * 1024 + cc * 256 + lm;
#pragma unroll
      for (int t = 0; t < 16; ++t)
#pragma unroll
        for (int q = 0; q < 4; ++q)
          op[(size_t)q * 4096 + t * 16] = acc2[t][q];
    }
  }
}

extern "C" void kernel_launch(void* const* d_in, const int* in_sizes, int n_in,
                              void* d_out, int out_size, void* d_ws, size_t ws_size,
                              hipStream_t stream) {
  const float* x  = (const float*)d_in[0];
  const float* Af = (const float*)d_in[1];
  const float* Bf = (const float*)d_in[2];
  const float* Am = (const float*)d_in[3];
  const float* Bm = (const float*)d_in[4];
  const float* As = (const float*)d_in[5];
  const float* Bs = (const float*)d_in[6];
  float* out = (float*)d_out;

  char* ws = (char*)d_ws;
  short* Apack = (short*)ws;                  // 786432 B
  short* Bpack = (short*)(ws + 786432);       // 786432 B

  hipLaunchKernelGGL(pack_AB, dim3(3072), dim3(256), 0, stream,
                     Af, Am, As, Bf, Bm, Bs, Apack, Bpack);
  hipLaunchKernelGGL(lora_fused, dim3(512), dim3(512), 0, stream, x, Apack, Bpack, out);
}